// Round 1
// baseline (173.124 us; speedup 1.0000x reference)
//
#include <hip/hip_runtime.h>
#include <hip/hip_cooperative_groups.h>
#include <math.h>

namespace cg = cooperative_groups;

#define SRATE 48000
#define NN    480000
#define MAXD  50
#define TPB   256
#define NV4   (NN / 4)                     // 120000 float4 segments
#define NBLKS ((NV4 + TPB - 1) / TPB)      // 469 blocks

__device__ __forceinline__ float clampf(float v, float lo, float hi) {
    return fminf(fmaxf(v, lo), hi);
}

struct Params { float al, bl, ah, bh, feedback, gain; int dl, nd; };

__device__ __forceinline__ Params load_params(const float* __restrict__ p) {
    Params q;
    float freq  = clampf(p[0], 20.0f, (float)(SRATE / 2));
    q.feedback  = clampf(p[1], 0.0f, 0.99f);
    float alow  = clampf(p[2], 1e-7f, 0.99f);
    float ahigh = clampf(p[3], 1e-7f, 0.99f);
    q.gain      = fmaxf(p[4], 1e-7f);
    float dlf   = clampf(floorf((float)SRATE / freq), 1.0f, (float)(NN / 2));
    q.dl = (int)dlf;
    q.nd = min(NN / q.dl, MAXD);
    q.al = alow;  q.bl = 1.0f - alow;
    q.ah = ahigh; q.bh = 1.0f - ahigh;
    return q;
}

// Thread-local affine over a float4 segment: state_out = Y + D*state_in.
__device__ __forceinline__ void seg_affine(const float4& v, float a, float b,
                                           float& Y, float& D) {
    float t = v.x;
    t = fmaf(t, b, v.y);
    t = fmaf(t, b, v.z);
    t = fmaf(t, b, v.w);
    Y = a * t;
    float b2 = b * b;
    D = b2 * b2;
}

// Wave-level inclusive scan of affine pairs (composition: later ∘ earlier).
__device__ __forceinline__ void wave_scan(int lane, float& Yl, float& Dl,
                                          float& Yh, float& Dh) {
    for (int off = 1; off < 64; off <<= 1) {
        float pYl = __shfl_up(Yl, off), pDl = __shfl_up(Dl, off);
        float pYh = __shfl_up(Yh, off), pDh = __shfl_up(Dh, off);
        if (lane >= off) {
            Yl = fmaf(Dl, pYl, Yl); Dl *= pDl;
            Yh = fmaf(Dh, pYh, Yh); Dh *= pDh;
        }
    }
}

// Single fused kernel: phase1 (block aggregates) -> grid.sync ->
// phase2 (block-carry scan + apply, filtered write) -> grid.sync ->
// phase3 (taps + tanh). Block-local scan state survives in regs/LDS
// across the syncs, removing kernel B's redundant dbuf re-read+rescan.
__global__ __launch_bounds__(TPB, 2) void fused(
    const float* __restrict__ x,        // delay_buffer
    const float* __restrict__ input,    // input_signal
    const float* __restrict__ p,        // parameters
    float4* __restrict__ blkAgg,
    float* __restrict__ filtered,
    float* __restrict__ out)
{
    cg::grid_group grid = cg::this_grid();
    Params q = load_params(p);
    const int tid  = threadIdx.x;
    const int lane = tid & 63;
    const int w    = tid >> 6;
    const int t    = blockIdx.x * TPB + tid;
    const bool valid = (t < NV4);

    // ---------------- phase 1: per-block affine aggregate ----------------
    float4 v = make_float4(0.f, 0.f, 0.f, 0.f);
    float Yl = 0.f, Dl = 1.f, Yh = 0.f, Dh = 1.f;
    if (valid) {
        v = ((const float4*)x)[t];
        seg_affine(v, q.al, q.bl, Yl, Dl);
        seg_affine(v, q.ah, q.bh, Yh, Dh);
    }
    wave_scan(lane, Yl, Dl, Yh, Dh);

    __shared__ float wYl[4], wDl[4], wYh[4], wDh[4];   // per-wave carries (persist!)
    if (lane == 63) { wYl[w] = Yl; wDl[w] = Dl; wYh[w] = Yh; wDh[w] = Dh; }
    __syncthreads();
    if (tid == TPB - 1) {                 // lane 63 of wave 3 holds its inclusive
        float cYl = 0.f, cDl = 1.f, cYh = 0.f, cDh = 1.f;
        for (int j = 0; j < 3; ++j) {     // compose waves 0..2 in order
            cYl = fmaf(wDl[j], cYl, wYl[j]); cDl *= wDl[j];
            cYh = fmaf(wDh[j], cYh, wYh[j]); cDh *= wDh[j];
        }
        blkAgg[blockIdx.x] = make_float4(fmaf(Dl, cYl, Yl), Dl * cDl,
                                         fmaf(Dh, cYh, Yh), Dh * cDh);
    }
    grid.sync();

    // -------- phase 2: block-carry scan (shfl-based) + apply + write --------
    // Pair-compose 469 aggregates into 235 pairs, one per thread, then a
    // register wave-scan + 4-entry cross-wave compose (2 barriers, not 16).
    float aYl = 0.f, aDl = 1.f, aYh = 0.f, aDh = 1.f;
    {
        int i2 = 2 * tid;
        float4 a0 = (i2     < NBLKS) ? blkAgg[i2]     : make_float4(0.f, 1.f, 0.f, 1.f);
        float4 a1 = (i2 + 1 < NBLKS) ? blkAgg[i2 + 1] : make_float4(0.f, 1.f, 0.f, 1.f);
        aYl = fmaf(a1.y, a0.x, a1.x); aDl = a1.y * a0.y;
        aYh = fmaf(a1.w, a0.z, a1.z); aDh = a1.w * a0.w;
    }
    wave_scan(lane, aYl, aDl, aYh, aDh);
    __shared__ float uYl[4], uDl[4], uYh[4], uDh[4];
    if (lane == 63) { uYl[w] = aYl; uDl[w] = aDl; uYh[w] = aYh; uDh[w] = aDh; }
    __syncthreads();
    {
        float pYl = 0.f, pDl = 1.f, pYh = 0.f, pDh = 1.f;
        for (int j = 0; j < 3; ++j) if (j < w) {
            pYl = fmaf(uDl[j], pYl, uYl[j]); pDl *= uDl[j];
            pYh = fmaf(uDh[j], pYh, uYh[j]); pDh *= uDh[j];
        }
        aYl = fmaf(aDl, pYl, aYl); aDl *= pDl;    // inclusive scan at pair tid
        aYh = fmaf(aDh, pYh, aYh); aDh *= pDh;
    }
    __shared__ float sYl[TPB], sDl[TPB], sYh[TPB], sDh[TPB];
    sYl[tid] = aYl; sDl[tid] = aDl; sYh[tid] = aYh; sDh[tid] = aDh;
    __syncthreads();
    __shared__ float GYl_s, GYh_s;
    if (tid == 0) {
        int b = blockIdx.x;
        int qq = b >> 1;
        float GYl = 0.f, GDl = 1.f, GYh = 0.f, GDh = 1.f;
        if (qq > 0) { GYl = sYl[qq-1]; GDl = sDl[qq-1];
                      GYh = sYh[qq-1]; GDh = sDh[qq-1]; }
        if (b & 1) {                      // odd block: also fold in block 2q
            float4 am = blkAgg[2 * qq];
            GYl = fmaf(am.y, GYl, am.x); GDl = am.y * GDl;
            GYh = fmaf(am.w, GYh, am.z); GDh = am.w * GDh;
        }
        (void)GDl; (void)GDh;             // initial state is 0: only Y matters
        GYl_s = GYl; GYh_s = GYh;
    }
    __syncthreads();

    // per-thread entering state = (laneExcl ∘ waveCarry) applied to block carry
    // (Yl..Dh and wYl[] still hold phase-1 results — no recompute)
    float eYl = __shfl_up(Yl, 1), eDl = __shfl_up(Dl, 1);
    float eYh = __shfl_up(Yh, 1), eDh = __shfl_up(Dh, 1);
    if (lane == 0) { eYl = 0.f; eDl = 1.f; eYh = 0.f; eDh = 1.f; }
    float cYl = 0.f, cDl = 1.f, cYh = 0.f, cDh = 1.f;
    for (int j = 0; j < 3; ++j) {
        if (j < w) {
            cYl = fmaf(wDl[j], cYl, wYl[j]); cDl *= wDl[j];
            cYh = fmaf(wDh[j], cYh, wYh[j]); cDh *= wDh[j];
        }
    }
    float BYl = fmaf(eDl, cYl, eYl), BDl = eDl * cDl;
    float BYh = fmaf(eDh, cYh, eYh), BDh = eDh * cDh;
    float yl = fmaf(BDl, GYl_s, BYl);
    float yh = fmaf(BDh, GYh_s, BYh);

    if (valid) {
        float4 o;
        yl = fmaf(q.bl, yl, q.al * v.x); yh = fmaf(q.bh, yh, q.ah * v.x); o.x = yh - yl;
        yl = fmaf(q.bl, yl, q.al * v.y); yh = fmaf(q.bh, yh, q.ah * v.y); o.y = yh - yl;
        yl = fmaf(q.bl, yl, q.al * v.z); yh = fmaf(q.bh, yh, q.ah * v.z); o.z = yh - yl;
        yl = fmaf(q.bl, yl, q.al * v.w); yh = fmaf(q.bh, yh, q.ah * v.w); o.w = yh - yl;
        ((float4*)filtered)[t] = o;
    }
    grid.sync();

    // ---------------- phase 3: taps + tanh ----------------
    if (valid) {
        int n0 = t * 4;
        float4 in4 = ((const float4*)input)[t];
        float a0 = in4.x, a1 = in4.y, a2 = in4.z, a3 = in4.w;

        if ((q.dl & 3) == 0) {
            int m = min(q.nd - 1, n0 / q.dl);     // taps valid for all 4 lanes
            int s = q.dl;
            float wgt = q.feedback;
            for (int i = 1; i <= m; ++i) {
                float4 f = *(const float4*)(filtered + (n0 - s));
                a0 = fmaf(wgt, f.x, a0);
                a1 = fmaf(wgt, f.y, a1);
                a2 = fmaf(wgt, f.z, a2);
                a3 = fmaf(wgt, f.w, a3);
                s += q.dl;
                wgt *= q.feedback;
            }
        } else {
            int s = q.dl;
            float wgt = q.feedback;
            for (int i = 1; i < q.nd; ++i) {
                if (s > n0 + 3) break;
                int b0 = n0 - s, b1 = b0 + 1, b2 = b0 + 2, b3 = b0 + 3;
                float f0 = (b0 >= 0) ? filtered[b0] : 0.f;
                float f1 = (b1 >= 0) ? filtered[b1] : 0.f;
                float f2 = (b2 >= 0) ? filtered[b2] : 0.f;
                float f3 = (b3 >= 0) ? filtered[b3] : 0.f;
                a0 = fmaf(wgt, f0, a0);
                a1 = fmaf(wgt, f1, a1);
                a2 = fmaf(wgt, f2, a2);
                a3 = fmaf(wgt, f3, a3);
                s += q.dl;
                wgt *= q.feedback;
            }
        }
        float4 o;
        o.x = tanhf(a0 * q.gain);
        o.y = tanhf(a1 * q.gain);
        o.z = tanhf(a2 * q.gain);
        o.w = tanhf(a3 * q.gain);
        ((float4*)out)[t] = o;
    }
}

extern "C" void kernel_launch(void* const* d_in, const int* in_sizes, int n_in,
                              void* d_out, int out_size, void* d_ws, size_t ws_size,
                              hipStream_t stream)
{
    const float* input  = (const float*)d_in[0];
    const float* params = (const float*)d_in[1];
    const float* dbuf   = (const float*)d_in[2];
    float* out = (float*)d_out;

    float* ws       = (float*)d_ws;
    float* filtered = ws;                         // NN floats (16B-aligned)
    float4* blkAgg  = (float4*)(ws + NN);         // NBLKS float4s

    void* args[] = { (void*)&dbuf, (void*)&input, (void*)&params,
                     (void*)&blkAgg, (void*)&filtered, (void*)&out };
    hipLaunchCooperativeKernel((void*)fused, dim3(NBLKS), dim3(TPB),
                               args, 0, stream);
}

// Round 2
// 102.134 us; speedup vs baseline: 1.6951x; 1.6951x over previous
//
#include <hip/hip_runtime.h>
#include <math.h>

#define SRATE 48000
#define NN    480000
#define MAXD  50
#define TPB   256
#define NV4   (NN / 4)                     // 120000 float4 segments
#define NBLKS ((NV4 + TPB - 1) / TPB)      // 469 blocks

typedef unsigned long long u64;
typedef unsigned int u32;

#define SCOPE_AGENT __HIP_MEMORY_SCOPE_AGENT

__device__ __forceinline__ float clampf(float v, float lo, float hi) {
    return fminf(fmaxf(v, lo), hi);
}

struct Params { float al, bl, ah, bh, feedback, gain; int dl, nd; };

__device__ __forceinline__ Params load_params(const float* __restrict__ p) {
    Params q;
    float freq  = clampf(p[0], 20.0f, (float)(SRATE / 2));
    q.feedback  = clampf(p[1], 0.0f, 0.99f);
    float alow  = clampf(p[2], 1e-7f, 0.99f);
    float ahigh = clampf(p[3], 1e-7f, 0.99f);
    q.gain      = fmaxf(p[4], 1e-7f);
    float dlf   = clampf(floorf((float)SRATE / freq), 1.0f, (float)(NN / 2));
    q.dl = (int)dlf;
    q.nd = min(NN / q.dl, MAXD);
    q.al = alow;  q.bl = 1.0f - alow;
    q.ah = ahigh; q.bh = 1.0f - ahigh;
    return q;
}

// Thread-local affine over a float4 segment: state_out = Y + D*state_in.
__device__ __forceinline__ void seg_affine(const float4& v, float a, float b,
                                           float& Y, float& D) {
    float t = v.x;
    t = fmaf(t, b, v.y);
    t = fmaf(t, b, v.z);
    t = fmaf(t, b, v.w);
    Y = a * t;
    float b2 = b * b;
    D = b2 * b2;
}

// Wave-level inclusive scan of affine pairs (composition: later ∘ earlier).
__device__ __forceinline__ void wave_scan(int lane, float& Yl, float& Dl,
                                          float& Yh, float& Dh) {
    for (int off = 1; off < 64; off <<= 1) {
        float pYl = __shfl_up(Yl, off), pDl = __shfl_up(Dl, off);
        float pYh = __shfl_up(Yh, off), pDh = __shfl_up(Dh, off);
        if (lane >= off) {
            Yl = fmaf(Dl, pYl, Yl); Dl *= pDl;
            Yh = fmaf(Dh, pYh, Yh); Dh *= pDh;
        }
    }
}

__device__ __forceinline__ u64 packf2(float a, float b) {
    return ((u64)__float_as_uint(b) << 32) | (u64)__float_as_uint(a);
}
__device__ __forceinline__ void unpackf2(u64 u, float& a, float& b) {
    a = __uint_as_float((u32)u);
    b = __uint_as_float((u32)(u >> 32));
}

// Single-pass scan with decoupled lookback (rocPRIM pattern).
// Publication protocol: agg/pref values are agent-scope relaxed u64 atomics
// (coherence point = L3), flag is a release-store (0=none, 1=agg, 2=prefix).
// Separate agg/pref slots avoid tearing when flag upgrades 1->2.
__global__ __launch_bounds__(TPB) void scan_lookback(
    const float* __restrict__ x, const float* __restrict__ p,
    u64* __restrict__ aggA, u64* __restrict__ aggB,
    u64* __restrict__ prefA, u64* __restrict__ prefB,
    u32* __restrict__ flags, float* __restrict__ filtered)
{
    Params q = load_params(p);
    const int tid  = threadIdx.x;
    const int lane = tid & 63;
    const int w    = tid >> 6;
    const int b    = blockIdx.x;
    const int t    = b * TPB + tid;
    const bool valid = (t < NV4);

    // ---- phase 1: thread/wave-local affine scan ----
    float4 v = make_float4(0.f, 0.f, 0.f, 0.f);
    float Yl = 0.f, Dl = 1.f, Yh = 0.f, Dh = 1.f;
    if (valid) {
        v = ((const float4*)x)[t];
        seg_affine(v, q.al, q.bl, Yl, Dl);
        seg_affine(v, q.ah, q.bh, Yh, Dh);
    }
    wave_scan(lane, Yl, Dl, Yh, Dh);

    __shared__ float wYl[4], wDl[4], wYh[4], wDh[4];
    __shared__ float sAgg[4];   // block aggregate (Yl,Dl,Yh,Dh)
    __shared__ float exc[4];    // exclusive block prefix
    if (lane == 63) { wYl[w] = Yl; wDl[w] = Dl; wYh[w] = Yh; wDh[w] = Dh; }
    __syncthreads();

    // ---- publish aggregate ASAP (thread 255) ----
    if (tid == TPB - 1) {
        float cYl = 0.f, cDl = 1.f, cYh = 0.f, cDh = 1.f;
        for (int j = 0; j < 3; ++j) {
            cYl = fmaf(wDl[j], cYl, wYl[j]); cDl *= wDl[j];
            cYh = fmaf(wDh[j], cYh, wYh[j]); cDh *= wDh[j];
        }
        float AYl = fmaf(Dl, cYl, Yl), ADl = Dl * cDl;
        float AYh = fmaf(Dh, cYh, Yh), ADh = Dh * cDh;
        sAgg[0] = AYl; sAgg[1] = ADl; sAgg[2] = AYh; sAgg[3] = ADh;
        if (b == 0) {   // block 0: aggregate IS the inclusive prefix
            __hip_atomic_store(&prefA[0], packf2(AYl, ADl), __ATOMIC_RELAXED, SCOPE_AGENT);
            __hip_atomic_store(&prefB[0], packf2(AYh, ADh), __ATOMIC_RELAXED, SCOPE_AGENT);
            __hip_atomic_store(&flags[0], 2u, __ATOMIC_RELEASE, SCOPE_AGENT);
        } else {
            __hip_atomic_store(&aggA[b], packf2(AYl, ADl), __ATOMIC_RELAXED, SCOPE_AGENT);
            __hip_atomic_store(&aggB[b], packf2(AYh, ADh), __ATOMIC_RELAXED, SCOPE_AGENT);
            __hip_atomic_store(&flags[b], 1u, __ATOMIC_RELEASE, SCOPE_AGENT);
        }
    }

    // ---- lookback by wave 0 (windows of 64 predecessors) ----
    if (b == 0) {
        if (tid == 0) { exc[0] = 0.f; exc[1] = 1.f; exc[2] = 0.f; exc[3] = 1.f; }
    } else if (w == 0) {
        float EYl = 0.f, EDl = 1.f, EYh = 0.f, EDh = 1.f;   // lane 0 only
        int base = b - 1;
        for (;;) {
            int idx = base - lane;                // lane 0 = nearest (latest)
            bool have = (idx >= 0);
            u32 f = 0;
            if (have) {
                f = __hip_atomic_load(&flags[idx], __ATOMIC_RELAXED, SCOPE_AGENT);
                while (f == 0u)
                    f = __hip_atomic_load(&flags[idx], __ATOMIC_RELAXED, SCOPE_AGENT);
            }
            __builtin_amdgcn_fence(__ATOMIC_ACQUIRE, "agent");
            u64 m2 = __ballot(have && (f == 2u));
            int F = (m2 != 0ull) ? (int)__builtin_ctzll(m2) : 63;  // nearest prefix
            float vYl = 0.f, vDl = 1.f, vYh = 0.f, vDh = 1.f;      // identity
            if (have && lane <= F) {
                u64 uA, uB;
                if (lane == F && f == 2u) {
                    uA = __hip_atomic_load(&prefA[idx], __ATOMIC_RELAXED, SCOPE_AGENT);
                    uB = __hip_atomic_load(&prefB[idx], __ATOMIC_RELAXED, SCOPE_AGENT);
                } else {
                    uA = __hip_atomic_load(&aggA[idx], __ATOMIC_RELAXED, SCOPE_AGENT);
                    uB = __hip_atomic_load(&aggB[idx], __ATOMIC_RELAXED, SCOPE_AGENT);
                }
                unpackf2(uA, vYl, vDl);
                unpackf2(uB, vYh, vDh);
            }
            // ordered fold x0∘x1∘...∘x63 (self=later, lane+off=earlier);
            // increasing offsets keep the non-commutative composition ordered.
            for (int off = 1; off < 64; off <<= 1) {
                float oYl = __shfl_down(vYl, off), oDl = __shfl_down(vDl, off);
                float oYh = __shfl_down(vYh, off), oDh = __shfl_down(vDh, off);
                if (lane + off < 64) {
                    vYl = fmaf(vDl, oYl, vYl); vDl *= oDl;
                    vYh = fmaf(vDh, oYh, vYh); vDh *= oDh;
                }
            }
            if (lane == 0) {    // E (later) ∘ window (earlier)
                EYl = fmaf(EDl, vYl, EYl); EDl *= vDl;
                EYh = fmaf(EDh, vYh, EYh); EDh *= vDh;
            }
            if (m2 != 0ull) break;   // window contained a prefix → done
            base -= 64;              // all aggregates: keep looking back
        }
        if (lane == 0) { exc[0] = EYl; exc[1] = EDl; exc[2] = EYh; exc[3] = EDh; }
    }
    __syncthreads();

    const float EYl = exc[0], EDl = exc[1], EYh = exc[2], EDh = exc[3];

    // ---- publish inclusive prefix (unblocks later blocks' lookbacks) ----
    if (b > 0 && tid == 0) {
        float AYl = sAgg[0], ADl = sAgg[1], AYh = sAgg[2], ADh = sAgg[3];
        float PYl = fmaf(ADl, EYl, AYl), PDl = ADl * EDl;
        float PYh = fmaf(ADh, EYh, AYh), PDh = ADh * EDh;
        __hip_atomic_store(&prefA[b], packf2(PYl, PDl), __ATOMIC_RELAXED, SCOPE_AGENT);
        __hip_atomic_store(&prefB[b], packf2(PYh, PDh), __ATOMIC_RELAXED, SCOPE_AGENT);
        __hip_atomic_store(&flags[b], 2u, __ATOMIC_RELEASE, SCOPE_AGENT);
    }

    // ---- apply: per-thread entering state, then 4 IIR steps + write ----
    float eYl = __shfl_up(Yl, 1), eDl = __shfl_up(Dl, 1);
    float eYh = __shfl_up(Yh, 1), eDh = __shfl_up(Dh, 1);
    if (lane == 0) { eYl = 0.f; eDl = 1.f; eYh = 0.f; eDh = 1.f; }
    float cYl = 0.f, cDl = 1.f, cYh = 0.f, cDh = 1.f;
    for (int j = 0; j < 3; ++j) {
        if (j < w) {
            cYl = fmaf(wDl[j], cYl, wYl[j]); cDl *= wDl[j];
            cYh = fmaf(wDh[j], cYh, wYh[j]); cDh *= wDh[j];
        }
    }
    float BYl = fmaf(eDl, cYl, eYl), BDl = eDl * cDl;
    float BYh = fmaf(eDh, cYh, eYh), BDh = eDh * cDh;
    float yl = fmaf(BDl, EYl, BYl);     // initial state 0: only Y of E matters
    float yh = fmaf(BDh, EYh, BYh);

    if (valid) {
        float4 o;
        yl = fmaf(q.bl, yl, q.al * v.x); yh = fmaf(q.bh, yh, q.ah * v.x); o.x = yh - yl;
        yl = fmaf(q.bl, yl, q.al * v.y); yh = fmaf(q.bh, yh, q.ah * v.y); o.y = yh - yl;
        yl = fmaf(q.bl, yl, q.al * v.z); yh = fmaf(q.bh, yh, q.ah * v.z); o.z = yh - yl;
        yl = fmaf(q.bl, yl, q.al * v.w); yh = fmaf(q.bh, yh, q.ah * v.w); o.w = yh - yl;
        ((float4*)filtered)[t] = o;
    }
}

// Taps + tanh (unchanged, known-good). Kernel boundary provides coherence
// for `filtered` across XCDs.
__global__ __launch_bounds__(TPB) void taps_kernel(
    const float* __restrict__ input, const float* __restrict__ p,
    const float* __restrict__ filtered, float* __restrict__ out)
{
    int t = blockIdx.x * TPB + threadIdx.x;
    if (t >= NV4) return;
    Params q = load_params(p);
    int n0 = t * 4;
    float4 in4 = ((const float4*)input)[t];
    float a0 = in4.x, a1 = in4.y, a2 = in4.z, a3 = in4.w;

    if ((q.dl & 3) == 0) {
        int m = min(q.nd - 1, n0 / q.dl);     // taps valid for all 4 lanes
        int s = q.dl;
        float wgt = q.feedback;
        for (int i = 1; i <= m; ++i) {
            float4 f = *(const float4*)(filtered + (n0 - s));
            a0 = fmaf(wgt, f.x, a0);
            a1 = fmaf(wgt, f.y, a1);
            a2 = fmaf(wgt, f.z, a2);
            a3 = fmaf(wgt, f.w, a3);
            s += q.dl;
            wgt *= q.feedback;
        }
    } else {
        int s = q.dl;
        float wgt = q.feedback;
        for (int i = 1; i < q.nd; ++i) {
            if (s > n0 + 3) break;
            int b0 = n0 - s, b1 = b0 + 1, b2 = b0 + 2, b3 = b0 + 3;
            float f0 = (b0 >= 0) ? filtered[b0] : 0.f;
            float f1 = (b1 >= 0) ? filtered[b1] : 0.f;
            float f2 = (b2 >= 0) ? filtered[b2] : 0.f;
            float f3 = (b3 >= 0) ? filtered[b3] : 0.f;
            a0 = fmaf(wgt, f0, a0);
            a1 = fmaf(wgt, f1, a1);
            a2 = fmaf(wgt, f2, a2);
            a3 = fmaf(wgt, f3, a3);
            s += q.dl;
            wgt *= q.feedback;
        }
    }
    float4 o;
    o.x = tanhf(a0 * q.gain);
    o.y = tanhf(a1 * q.gain);
    o.z = tanhf(a2 * q.gain);
    o.w = tanhf(a3 * q.gain);
    ((float4*)out)[t] = o;
}

extern "C" void kernel_launch(void* const* d_in, const int* in_sizes, int n_in,
                              void* d_out, int out_size, void* d_ws, size_t ws_size,
                              hipStream_t stream)
{
    const float* input  = (const float*)d_in[0];
    const float* params = (const float*)d_in[1];
    const float* dbuf   = (const float*)d_in[2];
    float* out = (float*)d_out;

    float* ws       = (float*)d_ws;
    float* filtered = ws;                          // NN floats (16B-aligned)
    u64*   aggA     = (u64*)(ws + NN);             // NBLKS u64 (8B-aligned)
    u64*   aggB     = aggA  + NBLKS;
    u64*   prefA    = aggB  + NBLKS;
    u64*   prefB    = prefA + NBLKS;
    u32*   flags    = (u32*)(prefB + NBLKS);       // NBLKS u32

    hipMemsetAsync(flags, 0, NBLKS * sizeof(u32), stream);
    scan_lookback<<<NBLKS, TPB, 0, stream>>>(dbuf, params, aggA, aggB,
                                             prefA, prefB, flags, filtered);
    taps_kernel<<<NBLKS, TPB, 0, stream>>>(input, params, filtered, out);
}

// Round 3
// 74.378 us; speedup vs baseline: 2.3276x; 1.3732x over previous
//
#include <hip/hip_runtime.h>
#include <math.h>

#define SRATE 48000
#define NN    480000
#define MAXD  50
#define TPB   256
#define NV4   (NN / 4)                     // 120000 float4 segments
#define NBLKS ((NV4 + TPB - 1) / TPB)      // 469 blocks
#define WARM  3072                         // warm-up samples (fast path)

__device__ __forceinline__ float clampf(float v, float lo, float hi) {
    return fminf(fmaxf(v, lo), hi);
}

struct Params { float al, bl, ah, bh, feedback, gain; int dl, nd; };

__device__ __forceinline__ Params load_params(const float* __restrict__ p) {
    Params q;
    float freq  = clampf(p[0], 20.0f, (float)(SRATE / 2));
    q.feedback  = clampf(p[1], 0.0f, 0.99f);
    float alow  = clampf(p[2], 1e-7f, 0.99f);
    float ahigh = clampf(p[3], 1e-7f, 0.99f);
    q.gain      = fmaxf(p[4], 1e-7f);
    float dlf   = clampf(floorf((float)SRATE / freq), 1.0f, (float)(NN / 2));
    q.dl = (int)dlf;
    q.nd = min(NN / q.dl, MAXD);
    q.al = alow;  q.bl = 1.0f - alow;
    q.ah = ahigh; q.bh = 1.0f - ahigh;
    return q;
}

// Uniform, deterministic across all kernels: carries decay below 1e-9
// within WARM samples -> blocks are independent (no cross-block scan).
__device__ __forceinline__ bool fast_path(const Params& q) {
    float bmax = fmaxf(q.bl, q.bh);
    return (float)WARM * logf(bmax) <= -20.0f;   // bmax^WARM <= ~2e-9
}

// Thread-local affine over a float4 segment: state_out = Y + D*state_in.
__device__ __forceinline__ void seg_affine(const float4& v, float a, float b,
                                           float& Y, float& D) {
    float t = v.x;
    t = fmaf(t, b, v.y);
    t = fmaf(t, b, v.z);
    t = fmaf(t, b, v.w);
    Y = a * t;
    float b2 = b * b;
    D = b2 * b2;
}

// Wave-level inclusive scan of affine pairs (composition: later ∘ earlier).
__device__ __forceinline__ void wave_scan(int lane, float& Yl, float& Dl,
                                          float& Yh, float& Dh) {
    for (int off = 1; off < 64; off <<= 1) {
        float pYl = __shfl_up(Yl, off), pDl = __shfl_up(Dl, off);
        float pYh = __shfl_up(Yh, off), pDh = __shfl_up(Dh, off);
        if (lane >= off) {
            Yl = fmaf(Dl, pYl, Yl); Dl *= pDl;
            Yh = fmaf(Dh, pYh, Yh); Dh *= pDh;
        }
    }
}

// Taps + tanh body (shared by k2-fast and k3-slow). Proven round-0 code.
__device__ __forceinline__ void taps_body(
    int t, const float* __restrict__ input, const Params& q,
    const float* __restrict__ filtered, float* __restrict__ out)
{
    int n0 = t * 4;
    float4 in4 = ((const float4*)input)[t];
    float a0 = in4.x, a1 = in4.y, a2 = in4.z, a3 = in4.w;

    if ((q.dl & 3) == 0) {
        int m = min(q.nd - 1, n0 / q.dl);     // taps valid for all 4 lanes
        int s = q.dl;
        float wgt = q.feedback;
        for (int i = 1; i <= m; ++i) {
            float4 f = *(const float4*)(filtered + (n0 - s));
            a0 = fmaf(wgt, f.x, a0);
            a1 = fmaf(wgt, f.y, a1);
            a2 = fmaf(wgt, f.z, a2);
            a3 = fmaf(wgt, f.w, a3);
            s += q.dl;
            wgt *= q.feedback;
        }
    } else {
        int s = q.dl;
        float wgt = q.feedback;
        for (int i = 1; i < q.nd; ++i) {
            if (s > n0 + 3) break;
            int b0 = n0 - s, b1 = b0 + 1, b2 = b0 + 2, b3 = b0 + 3;
            float f0 = (b0 >= 0) ? filtered[b0] : 0.f;
            float f1 = (b1 >= 0) ? filtered[b1] : 0.f;
            float f2 = (b2 >= 0) ? filtered[b2] : 0.f;
            float f3 = (b3 >= 0) ? filtered[b3] : 0.f;
            a0 = fmaf(wgt, f0, a0);
            a1 = fmaf(wgt, f1, a1);
            a2 = fmaf(wgt, f2, a2);
            a3 = fmaf(wgt, f3, a3);
            s += q.dl;
            wgt *= q.feedback;
        }
    }
    float4 o;
    o.x = tanhf(a0 * q.gain);
    o.y = tanhf(a1 * q.gain);
    o.z = tanhf(a2 * q.gain);
    o.w = tanhf(a3 * q.gain);
    ((float4*)out)[t] = o;
}

// k1: fast -> independent per-block filter (warm-up WARM, outputs 1024).
//     slow -> per-block affine aggregate (round-0 scan_agg).
__global__ __launch_bounds__(TPB) void k1_filter_or_agg(
    const float* __restrict__ x, const float* __restrict__ p,
    float4* __restrict__ blkAgg, float* __restrict__ filtered)
{
    Params q = load_params(p);
    const int tid  = threadIdx.x;
    const int lane = tid & 63;
    const int w    = tid >> 6;
    const int b    = blockIdx.x;
    __shared__ float wYl[4], wDl[4], wYh[4], wDh[4];

    if (fast_path(q)) {
        // span = [b*1024 - WARM, b*1024 + 1023]; 256 thr x 16 samples.
        // wave 3 (tid 192..255) holds the 1024 output samples exactly.
        const int segBase = ((b * 1024 - WARM) >> 2) + tid * 4;
        float4 v[4];
        #pragma unroll
        for (int k = 0; k < 4; ++k) {
            int s = segBase + k;
            v[k] = (s >= 0 && s < NV4) ? ((const float4*)x)[s]
                                       : make_float4(0.f, 0.f, 0.f, 0.f);
        }
        float Yl = 0.f, Dl = 1.f, Yh = 0.f, Dh = 1.f;
        #pragma unroll
        for (int k = 0; k < 4; ++k) {
            float y, d;
            seg_affine(v[k], q.al, q.bl, y, d);
            Yl = fmaf(d, Yl, y); Dl *= d;
            seg_affine(v[k], q.ah, q.bh, y, d);
            Yh = fmaf(d, Yh, y); Dh *= d;
        }
        wave_scan(lane, Yl, Dl, Yh, Dh);
        if (lane == 63) { wYl[w] = Yl; wDl[w] = Dl; wYh[w] = Yh; wDh[w] = Dh; }
        __syncthreads();
        if (w == 3) {                      // output wave only
            float eYl = __shfl_up(Yl, 1), eDl = __shfl_up(Dl, 1);
            float eYh = __shfl_up(Yh, 1), eDh = __shfl_up(Dh, 1);
            if (lane == 0) { eYl = 0.f; eDl = 1.f; eYh = 0.f; eDh = 1.f; }
            float cYl = 0.f, cDl = 1.f, cYh = 0.f, cDh = 1.f;
            #pragma unroll
            for (int j = 0; j < 3; ++j) {  // waves 0..2 carries
                cYl = fmaf(wDl[j], cYl, wYl[j]); cDl *= wDl[j];
                cYh = fmaf(wDh[j], cYh, wYh[j]); cDh *= wDh[j];
            }
            float yl = fmaf(eDl, cYl, eYl);   // span-start state = 0
            float yh = fmaf(eDh, cYh, eYh);
            #pragma unroll
            for (int k = 0; k < 4; ++k) {
                int s = segBase + k;
                float4 vv = v[k], o;
                yl = fmaf(q.bl, yl, q.al * vv.x); yh = fmaf(q.bh, yh, q.ah * vv.x); o.x = yh - yl;
                yl = fmaf(q.bl, yl, q.al * vv.y); yh = fmaf(q.bh, yh, q.ah * vv.y); o.y = yh - yl;
                yl = fmaf(q.bl, yl, q.al * vv.z); yh = fmaf(q.bh, yh, q.ah * vv.z); o.z = yh - yl;
                yl = fmaf(q.bl, yl, q.al * vv.w); yh = fmaf(q.bh, yh, q.ah * vv.w); o.w = yh - yl;
                if (s < NV4) ((float4*)filtered)[s] = o;
            }
        }
        return;
    }

    // ---------------- slow path: round-0 scan_agg ----------------
    int t = b * TPB + tid;
    float Yl = 0.f, Dl = 1.f, Yh = 0.f, Dh = 1.f;
    if (t < NV4) {
        float4 v = ((const float4*)x)[t];
        seg_affine(v, q.al, q.bl, Yl, Dl);
        seg_affine(v, q.ah, q.bh, Yh, Dh);
    }
    wave_scan(lane, Yl, Dl, Yh, Dh);
    if (lane == 63) { wYl[w] = Yl; wDl[w] = Dl; wYh[w] = Yh; wDh[w] = Dh; }
    __syncthreads();
    if (tid == TPB - 1) {
        float cYl = 0.f, cDl = 1.f, cYh = 0.f, cDh = 1.f;
        for (int j = 0; j < 3; ++j) {
            cYl = fmaf(wDl[j], cYl, wYl[j]); cDl *= wDl[j];
            cYh = fmaf(wDh[j], cYh, wYh[j]); cDh *= wDh[j];
        }
        float AYl = fmaf(Dl, cYl, Yl), ADl = Dl * cDl;
        float AYh = fmaf(Dh, cYh, Yh), ADh = Dh * cDh;
        blkAgg[b] = make_float4(AYl, ADl, AYh, ADh);
    }
}

// k2: fast -> taps+tanh. slow -> round-0 scan_apply.
__global__ __launch_bounds__(TPB) void k2_taps_or_apply(
    const float* __restrict__ x, const float* __restrict__ input,
    const float* __restrict__ p, const float4* __restrict__ blkAgg,
    float* __restrict__ filtered, float* __restrict__ out)
{
    Params q = load_params(p);
    const int tid  = threadIdx.x;
    const int lane = tid & 63;
    const int w    = tid >> 6;
    const int t    = blockIdx.x * TPB + tid;

    if (fast_path(q)) {
        if (t < NV4) taps_body(t, input, q, filtered, out);
        return;
    }

    // ---------------- slow path: round-0 scan_apply ----------------
    bool valid = (t < NV4);
    float4 v = make_float4(0.f, 0.f, 0.f, 0.f);
    float Yl = 0.f, Dl = 1.f, Yh = 0.f, Dh = 1.f;
    if (valid) {
        v = ((const float4*)x)[t];
        seg_affine(v, q.al, q.bl, Yl, Dl);
        seg_affine(v, q.ah, q.bh, Yh, Dh);
    }
    wave_scan(lane, Yl, Dl, Yh, Dh);

    __shared__ float wYl[4], wDl[4], wYh[4], wDh[4];
    if (lane == 63) { wYl[w] = Yl; wDl[w] = Dl; wYh[w] = Yh; wDh[w] = Dh; }

    __shared__ float sYl[TPB], sDl[TPB], sYh[TPB], sDh[TPB];
    {
        int i2 = 2 * tid;
        float4 a0 = (i2     < NBLKS) ? blkAgg[i2]     : make_float4(0.f, 1.f, 0.f, 1.f);
        float4 a1 = (i2 + 1 < NBLKS) ? blkAgg[i2 + 1] : make_float4(0.f, 1.f, 0.f, 1.f);
        sYl[tid] = fmaf(a1.y, a0.x, a1.x); sDl[tid] = a1.y * a0.y;
        sYh[tid] = fmaf(a1.w, a0.z, a1.z); sDh[tid] = a1.w * a0.w;
    }
    __syncthreads();
    for (int off = 1; off < TPB; off <<= 1) {
        float cyl = sYl[tid], cdl = sDl[tid], cyh = sYh[tid], cdh = sDh[tid];
        float pyl = 0.f, pdl = 1.f, pyh = 0.f, pdh = 1.f;
        bool has = (tid >= off);
        if (has) { pyl = sYl[tid-off]; pdl = sDl[tid-off];
                   pyh = sYh[tid-off]; pdh = sDh[tid-off]; }
        __syncthreads();
        if (has) {
            sYl[tid] = fmaf(cdl, pyl, cyl); sDl[tid] = cdl * pdl;
            sYh[tid] = fmaf(cdh, pyh, cyh); sDh[tid] = cdh * pdh;
        }
        __syncthreads();
    }
    __shared__ float GYl_s, GYh_s;
    if (tid == 0) {
        int b = blockIdx.x;
        int qq = b >> 1;
        float GYl = 0.f, GDl = 1.f, GYh = 0.f, GDh = 1.f;
        if (qq > 0) { GYl = sYl[qq-1]; GDl = sDl[qq-1];
                      GYh = sYh[qq-1]; GDh = sDh[qq-1]; }
        if (b & 1) {
            float4 am = blkAgg[2 * qq];
            GYl = fmaf(am.y, GYl, am.x); GDl = am.y * GDl;
            GYh = fmaf(am.w, GYh, am.z); GDh = am.w * GDh;
        }
        (void)GDl; (void)GDh;
        GYl_s = GYl; GYh_s = GYh;
    }
    __syncthreads();

    float eYl = __shfl_up(Yl, 1), eDl = __shfl_up(Dl, 1);
    float eYh = __shfl_up(Yh, 1), eDh = __shfl_up(Dh, 1);
    if (lane == 0) { eYl = 0.f; eDl = 1.f; eYh = 0.f; eDh = 1.f; }
    float cYl = 0.f, cDl = 1.f, cYh = 0.f, cDh = 1.f;
    for (int j = 0; j < 3; ++j) {
        if (j < w) {
            cYl = fmaf(wDl[j], cYl, wYl[j]); cDl *= wDl[j];
            cYh = fmaf(wDh[j], cYh, wYh[j]); cDh *= wDh[j];
        }
    }
    float BYl = fmaf(eDl, cYl, eYl), BDl = eDl * cDl;
    float BYh = fmaf(eDh, cYh, eYh), BDh = eDh * cDh;
    float yl = fmaf(BDl, GYl_s, BYl);
    float yh = fmaf(BDh, GYh_s, BYh);

    if (valid) {
        float4 o;
        yl = fmaf(q.bl, yl, q.al * v.x); yh = fmaf(q.bh, yh, q.ah * v.x); o.x = yh - yl;
        yl = fmaf(q.bl, yl, q.al * v.y); yh = fmaf(q.bh, yh, q.ah * v.y); o.y = yh - yl;
        yl = fmaf(q.bl, yl, q.al * v.z); yh = fmaf(q.bh, yh, q.ah * v.z); o.z = yh - yl;
        yl = fmaf(q.bl, yl, q.al * v.w); yh = fmaf(q.bh, yh, q.ah * v.w); o.w = yh - yl;
        ((float4*)filtered)[t] = o;
    }
}

// k3: fast -> stub. slow -> taps+tanh.
__global__ __launch_bounds__(TPB) void k3_taps_or_stub(
    const float* __restrict__ input, const float* __restrict__ p,
    const float* __restrict__ filtered, float* __restrict__ out)
{
    Params q = load_params(p);
    if (fast_path(q)) return;
    int t = blockIdx.x * TPB + threadIdx.x;
    if (t < NV4) taps_body(t, input, q, filtered, out);
}

extern "C" void kernel_launch(void* const* d_in, const int* in_sizes, int n_in,
                              void* d_out, int out_size, void* d_ws, size_t ws_size,
                              hipStream_t stream)
{
    const float* input  = (const float*)d_in[0];
    const float* params = (const float*)d_in[1];
    const float* dbuf   = (const float*)d_in[2];
    float* out = (float*)d_out;

    float* ws       = (float*)d_ws;
    float* filtered = ws;                         // NN floats (16B-aligned)
    float4* blkAgg  = (float4*)(ws + NN);         // NBLKS float4s

    k1_filter_or_agg<<<NBLKS, TPB, 0, stream>>>(dbuf, params, blkAgg, filtered);
    k2_taps_or_apply<<<NBLKS, TPB, 0, stream>>>(dbuf, input, params, blkAgg,
                                                filtered, out);
    k3_taps_or_stub <<<NBLKS, TPB, 0, stream>>>(input, params, filtered, out);
}

// Round 4
// 73.531 us; speedup vs baseline: 2.3544x; 1.0115x over previous
//
#include <hip/hip_runtime.h>
#include <math.h>

#define SRATE 48000
#define NN    480000
#define MAXD  50
#define TPB   256
#define NV4   (NN / 4)                     // 120000 float4 segments
#define NBLKS ((NV4 + TPB - 1) / TPB)      // 469 blocks

__device__ __forceinline__ float clampf(float v, float lo, float hi) {
    return fminf(fmaxf(v, lo), hi);
}

struct Params { float al, bl, ah, bh, feedback, gain; int dl, nd; };

__device__ __forceinline__ Params load_params(const float* __restrict__ p) {
    Params q;
    float freq  = clampf(p[0], 20.0f, (float)(SRATE / 2));
    q.feedback  = clampf(p[1], 0.0f, 0.99f);
    float alow  = clampf(p[2], 1e-7f, 0.99f);
    float ahigh = clampf(p[3], 1e-7f, 0.99f);
    q.gain      = fmaxf(p[4], 1e-7f);
    float dlf   = clampf(floorf((float)SRATE / freq), 1.0f, (float)(NN / 2));
    q.dl = (int)dlf;
    q.nd = min(NN / q.dl, MAXD);
    q.al = alow;  q.bl = 1.0f - alow;
    q.ah = ahigh; q.bh = 1.0f - ahigh;
    return q;
}

// Thread-local affine over a float4 segment: state_out = Y + D*state_in.
__device__ __forceinline__ void seg_affine(const float4& v, float a, float b,
                                           float& Y, float& D) {
    float t = v.x;
    t = fmaf(t, b, v.y);
    t = fmaf(t, b, v.z);
    t = fmaf(t, b, v.w);
    Y = a * t;
    float b2 = b * b;
    D = b2 * b2;
}

// Wave-level inclusive scan of affine pairs (composition: later ∘ earlier).
__device__ __forceinline__ void wave_scan(int lane, float& Yl, float& Dl,
                                          float& Yh, float& Dh) {
    for (int off = 1; off < 64; off <<= 1) {
        float pYl = __shfl_up(Yl, off), pDl = __shfl_up(Dl, off);
        float pYh = __shfl_up(Yh, off), pDh = __shfl_up(Dh, off);
        if (lane >= off) {
            Yl = fmaf(Dl, pYl, Yl); Dl *= pDl;
            Yh = fmaf(Dh, pYh, Yh); Dh *= pDh;
        }
    }
}

// Delay-sum of raw dbuf (taps commuted ahead of the bandpass):
// z[n] = sum_{i=1..nd-1, i*dl<=n} fb^i * dbuf[n - i*dl].
// Proven round-0 taps loop, accumulator starts at 0, source = dbuf.
__device__ __forceinline__ float4 delay_sum(
    int t, const float* __restrict__ dbuf, const Params& q)
{
    int n0 = t * 4;
    float a0 = 0.f, a1 = 0.f, a2 = 0.f, a3 = 0.f;

    if ((q.dl & 3) == 0) {
        int m = min(q.nd - 1, n0 / q.dl);     // taps valid for all 4 lanes
        int s = q.dl;
        float wgt = q.feedback;
        for (int i = 1; i <= m; ++i) {
            float4 f = *(const float4*)(dbuf + (n0 - s));
            a0 = fmaf(wgt, f.x, a0);
            a1 = fmaf(wgt, f.y, a1);
            a2 = fmaf(wgt, f.z, a2);
            a3 = fmaf(wgt, f.w, a3);
            s += q.dl;
            wgt *= q.feedback;
        }
    } else {
        int s = q.dl;
        float wgt = q.feedback;
        for (int i = 1; i < q.nd; ++i) {
            if (s > n0 + 3) break;
            int b0 = n0 - s, b1 = b0 + 1, b2 = b0 + 2, b3 = b0 + 3;
            float f0 = (b0 >= 0) ? dbuf[b0] : 0.f;
            float f1 = (b1 >= 0) ? dbuf[b1] : 0.f;
            float f2 = (b2 >= 0) ? dbuf[b2] : 0.f;
            float f3 = (b3 >= 0) ? dbuf[b3] : 0.f;
            a0 = fmaf(wgt, f0, a0);
            a1 = fmaf(wgt, f1, a1);
            a2 = fmaf(wgt, f2, a2);
            a3 = fmaf(wgt, f3, a3);
            s += q.dl;
            wgt *= q.feedback;
        }
    }
    return make_float4(a0, a1, a2, a3);
}

// k1: z = delay_sum(dbuf) (store to ws) + per-block affine aggregate of the
// two one-pole filters over z (proven scan_agg tail on in-register z).
__global__ __launch_bounds__(TPB) void k1_z_agg(
    const float* __restrict__ dbuf, const float* __restrict__ p,
    float* __restrict__ z, float4* __restrict__ blkAgg)
{
    Params q = load_params(p);
    const int tid  = threadIdx.x;
    const int lane = tid & 63;
    const int w    = tid >> 6;
    const int t    = blockIdx.x * TPB + tid;

    float Yl = 0.f, Dl = 1.f, Yh = 0.f, Dh = 1.f;
    if (t < NV4) {
        float4 v = delay_sum(t, dbuf, q);
        ((float4*)z)[t] = v;
        seg_affine(v, q.al, q.bl, Yl, Dl);
        seg_affine(v, q.ah, q.bh, Yh, Dh);
    }
    wave_scan(lane, Yl, Dl, Yh, Dh);

    __shared__ float wYl[4], wDl[4], wYh[4], wDh[4];
    if (lane == 63) { wYl[w] = Yl; wDl[w] = Dl; wYh[w] = Yh; wDh[w] = Dh; }
    __syncthreads();
    if (tid == TPB - 1) {                 // lane 63 of wave 3 holds its inclusive
        float cYl = 0.f, cDl = 1.f, cYh = 0.f, cDh = 1.f;
        for (int j = 0; j < 3; ++j) {     // compose waves 0..2 in order
            cYl = fmaf(wDl[j], cYl, wYl[j]); cDl *= wDl[j];
            cYh = fmaf(wDh[j], cYh, wYh[j]); cDh *= wDh[j];
        }
        float AYl = fmaf(Dl, cYl, Yl), ADl = Dl * cDl;
        float AYh = fmaf(Dh, cYh, Yh), ADh = Dh * cDh;
        blkAgg[blockIdx.x] = make_float4(AYl, ADl, AYh, ADh);
    }
}

// k2: cross-block carry scan + local rescan of z + apply both filters,
// then out = tanh(gain * (input + (yh - yl))). Proven scan_apply structure.
__global__ __launch_bounds__(TPB) void k2_apply_out(
    const float* __restrict__ z, const float* __restrict__ input,
    const float* __restrict__ p, const float4* __restrict__ blkAgg,
    float* __restrict__ out)
{
    Params q = load_params(p);
    const int tid  = threadIdx.x;
    const int lane = tid & 63;
    const int w    = tid >> 6;
    const int t    = blockIdx.x * TPB + tid;
    const bool valid = (t < NV4);

    float4 v = make_float4(0.f, 0.f, 0.f, 0.f);
    float Yl = 0.f, Dl = 1.f, Yh = 0.f, Dh = 1.f;
    if (valid) {
        v = ((const float4*)z)[t];
        seg_affine(v, q.al, q.bl, Yl, Dl);
        seg_affine(v, q.ah, q.bh, Yh, Dh);
    }
    wave_scan(lane, Yl, Dl, Yh, Dh);

    __shared__ float wYl[4], wDl[4], wYh[4], wDh[4];
    if (lane == 63) { wYl[w] = Yl; wDl[w] = Dl; wYh[w] = Yh; wDh[w] = Dh; }

    // ---- block-carry: scan 469 aggregates (pair-compose + Hillis-Steele) ----
    __shared__ float sYl[TPB], sDl[TPB], sYh[TPB], sDh[TPB];
    {
        int i2 = 2 * tid;
        float4 a0 = (i2     < NBLKS) ? blkAgg[i2]     : make_float4(0.f, 1.f, 0.f, 1.f);
        float4 a1 = (i2 + 1 < NBLKS) ? blkAgg[i2 + 1] : make_float4(0.f, 1.f, 0.f, 1.f);
        sYl[tid] = fmaf(a1.y, a0.x, a1.x); sDl[tid] = a1.y * a0.y;
        sYh[tid] = fmaf(a1.w, a0.z, a1.z); sDh[tid] = a1.w * a0.w;
    }
    __syncthreads();
    for (int off = 1; off < TPB; off <<= 1) {
        float cyl = sYl[tid], cdl = sDl[tid], cyh = sYh[tid], cdh = sDh[tid];
        float pyl = 0.f, pdl = 1.f, pyh = 0.f, pdh = 1.f;
        bool has = (tid >= off);
        if (has) { pyl = sYl[tid-off]; pdl = sDl[tid-off];
                   pyh = sYh[tid-off]; pdh = sDh[tid-off]; }
        __syncthreads();
        if (has) {
            sYl[tid] = fmaf(cdl, pyl, cyl); sDl[tid] = cdl * pdl;
            sYh[tid] = fmaf(cdh, pyh, cyh); sDh[tid] = cdh * pdh;
        }
        __syncthreads();
    }
    __shared__ float GYl_s, GYh_s;
    if (tid == 0) {
        int b = blockIdx.x;
        int qq = b >> 1;
        float GYl = 0.f, GDl = 1.f, GYh = 0.f, GDh = 1.f;
        if (qq > 0) { GYl = sYl[qq-1]; GDl = sDl[qq-1];
                      GYh = sYh[qq-1]; GDh = sDh[qq-1]; }
        if (b & 1) {                      // odd block: also fold in block 2q
            float4 am = blkAgg[2 * qq];
            GYl = fmaf(am.y, GYl, am.x); GDl = am.y * GDl;
            GYh = fmaf(am.w, GYh, am.z); GDh = am.w * GDh;
        }
        (void)GDl; (void)GDh;             // initial state is 0: only Y matters
        GYl_s = GYl; GYh_s = GYh;
    }
    __syncthreads();

    // per-thread entering state = (laneExcl ∘ waveCarry) applied to block carry
    float eYl = __shfl_up(Yl, 1), eDl = __shfl_up(Dl, 1);
    float eYh = __shfl_up(Yh, 1), eDh = __shfl_up(Dh, 1);
    if (lane == 0) { eYl = 0.f; eDl = 1.f; eYh = 0.f; eDh = 1.f; }
    float cYl = 0.f, cDl = 1.f, cYh = 0.f, cDh = 1.f;
    for (int j = 0; j < 3; ++j) {
        if (j < w) {
            cYl = fmaf(wDl[j], cYl, wYl[j]); cDl *= wDl[j];
            cYh = fmaf(wDh[j], cYh, wYh[j]); cDh *= wDh[j];
        }
    }
    float BYl = fmaf(eDl, cYl, eYl), BDl = eDl * cDl;
    float BYh = fmaf(eDh, cYh, eYh), BDh = eDh * cDh;
    float yl = fmaf(BDl, GYl_s, BYl);
    float yh = fmaf(BDh, GYh_s, BYh);

    if (valid) {
        float4 in4 = ((const float4*)input)[t];
        float4 o;
        yl = fmaf(q.bl, yl, q.al * v.x); yh = fmaf(q.bh, yh, q.ah * v.x);
        o.x = tanhf((in4.x + (yh - yl)) * q.gain);
        yl = fmaf(q.bl, yl, q.al * v.y); yh = fmaf(q.bh, yh, q.ah * v.y);
        o.y = tanhf((in4.y + (yh - yl)) * q.gain);
        yl = fmaf(q.bl, yl, q.al * v.z); yh = fmaf(q.bh, yh, q.ah * v.z);
        o.z = tanhf((in4.z + (yh - yl)) * q.gain);
        yl = fmaf(q.bl, yl, q.al * v.w); yh = fmaf(q.bh, yh, q.ah * v.w);
        o.w = tanhf((in4.w + (yh - yl)) * q.gain);
        ((float4*)out)[t] = o;
    }
}

extern "C" void kernel_launch(void* const* d_in, const int* in_sizes, int n_in,
                              void* d_out, int out_size, void* d_ws, size_t ws_size,
                              hipStream_t stream)
{
    const float* input  = (const float*)d_in[0];
    const float* params = (const float*)d_in[1];
    const float* dbuf   = (const float*)d_in[2];
    float* out = (float*)d_out;

    float* ws      = (float*)d_ws;
    float* z       = ws;                          // NN floats (16B-aligned)
    float4* blkAgg = (float4*)(ws + NN);          // NBLKS float4s

    k1_z_agg   <<<NBLKS, TPB, 0, stream>>>(dbuf, params, z, blkAgg);
    k2_apply_out<<<NBLKS, TPB, 0, stream>>>(z, input, params, blkAgg, out);
}